// Round 7
// baseline (413.149 us; speedup 1.0000x reference)
//
#include <hip/hip_runtime.h>

#define NN 50000
#define NE 800000
#define SCAN_B 256
#define SCAN_NB ((NN + SCAN_B - 1) / SCAN_B)   // 196

// setup kernel block partition
#define CVT_BLKS 6250                          // NN*128/4/256 exactly
#define PREP_BLKS 32
#define ZERO_BLKS 49                           // NN/4/256 rounded up
#define SETUP_GRID (CVT_BLKS + PREP_BLKS + ZERO_BLKS + 1)

typedef short short8 __attribute__((ext_vector_type(8)));
typedef short short4v __attribute__((ext_vector_type(4)));
typedef float f32x4 __attribute__((ext_vector_type(4)));

__device__ inline unsigned short bf16_rne(float f) {
    unsigned u = __float_as_uint(f);
    unsigned r = (u + 0x7fffu + ((u >> 16) & 1u)) >> 16;
    return (unsigned short)r;
}
__device__ inline float bf16_to_f32(unsigned short h) {
    return __uint_as_float((unsigned)h << 16);
}

// ---------------- fused setup: cvt x->bf16 | weight prep | zero deg | zero flags
__global__ __launch_bounds__(256) void setup_kernel(const float* __restrict__ x,
                                                    unsigned short* __restrict__ xb,
                                                    const float* __restrict__ W0,
                                                    const float* __restrict__ W1,
                                                    const float* __restrict__ W2,
                                                    const float* __restrict__ W3,
                                                    short* __restrict__ wf,
                                                    int* __restrict__ deg,
                                                    int* __restrict__ flags) {
    int b = blockIdx.x;
    if (b < CVT_BLKS) {                       // x -> bf16 (one float4/thread, exact)
        int i = b * 256 + threadIdx.x;
        float4 v = ((const float4*)x)[i];
        short4v r;
        r[0] = (short)bf16_rne(v.x);
        r[1] = (short)bf16_rne(v.y);
        r[2] = (short)bf16_rne(v.z);
        r[3] = (short)bf16_rne(v.w);
        ((short4v*)xb)[i] = r;
    } else if (b < CVT_BLKS + PREP_BLKS) {    // weight split+fragment reorder
        int t = (b - CVT_BLKS) * 256 + threadIdx.x;   // 0..8191
        int mat = t >> 11;
        const float* W = (mat == 0) ? W0 : (mat == 1) ? W1 : (mat == 2) ? W2 : W3;
        short* out = wf + (size_t)mat * 32768;
        int r = t & 2047;
        int nt = r >> 8;
        int kc = (r >> 6) & 3;
        int lane = r & 63;
        int n = nt * 16 + (lane & 15);
        int kbase = kc * 32 + ((lane >> 4) << 3);
        short8 vh, vl;
#pragma unroll
        for (int j = 0; j < 8; ++j) {
            float w = W[(size_t)(kbase + j) * 128 + n];
            unsigned short h = bf16_rne(w);
            unsigned short l = bf16_rne(w - bf16_to_f32(h));
            vh[j] = (short)h;
            vl[j] = (short)l;
        }
        size_t o = ((((size_t)nt * 4 + kc) * 2) * 64 + lane) * 8;
        *(short8*)(out + o) = vh;
        *(short8*)(out + o + 512) = vl;
    } else if (b < CVT_BLKS + PREP_BLKS + ZERO_BLKS) {  // zero deg (int4)
        int i = (b - CVT_BLKS - PREP_BLKS) * 256 + threadIdx.x;
        if (i < NN / 4) ((int4*)deg)[i] = make_int4(0, 0, 0, 0);
    } else {                                  // zero scan flags
        if (threadIdx.x < SCAN_NB) flags[threadIdx.x] = 0;
    }
}

// ---------------- CSR build ----------------
__global__ void hist_kernel(const int* __restrict__ dst, int* __restrict__ deg, int ne) {
    int e = blockIdx.x * blockDim.x + threadIdx.x;
    if (e < ne) atomicAdd(&deg[dst[e]], 1);
}

// single-dispatch chained prefix scan: flag value = prefix_inclusive + 1 (0 = not
// ready) so one device-scope atomic is both flag and payload. 196 blocks <= 256
// CUs -> all co-resident -> spin is deadlock-free.
__global__ __launch_bounds__(SCAN_B) void scan_chain_kernel(const int* __restrict__ deg,
                                                            int* __restrict__ row_ptr,
                                                            int* __restrict__ cursor,
                                                            float* __restrict__ inv_deg,
                                                            int* __restrict__ flags,
                                                            int n, int ne) {
    __shared__ int s[SCAN_B];
    __shared__ int sbase;
    int t = threadIdx.x, bid = blockIdx.x;
    int i = bid * SCAN_B + t;
    int v = (i < n) ? deg[i] : 0;
    s[t] = v;
    __syncthreads();
    for (int d = 1; d < SCAN_B; d <<= 1) {
        int u = (t >= d) ? s[t - d] : 0;
        __syncthreads();
        s[t] += u;
        __syncthreads();
    }
    if (t == 0) {
        int base = 0;
        if (bid > 0) {
            int f;
            while ((f = atomicAdd(&flags[bid - 1], 0)) == 0) __builtin_amdgcn_s_sleep(1);
            base = f - 1;
        }
        sbase = base;
        atomicExch(&flags[bid], base + s[SCAN_B - 1] + 1);
    }
    __syncthreads();
    int base = sbase;
    if (i < n) {
        int rp = base + s[t] - v;   // exclusive prefix
        row_ptr[i] = rp;
        cursor[i] = rp;
        inv_deg[i] = 1.0f / (float)(v > 0 ? v : 1);
    }
    if (i == 0) row_ptr[n] = ne;
}

__global__ void fill_kernel(const int* __restrict__ src, const int* __restrict__ dst,
                            int* __restrict__ cursor, int* __restrict__ col, int ne) {
    int e = blockIdx.x * blockDim.x + threadIdx.x;
    if (e >= ne) return;
    int d = dst[e];
    int pos = atomicAdd(&cursor[d], 1);
    col[pos] = src[e];
}

// ---------------- mean aggregation over bf16 features, fp32 accumulate ------
// one wave per node; slot = lane>>4 handles edge e = beg + i*4 + slot, sub =
// lane&15 handles features [sub*8, sub*8+8). 16B/lane loads, x2 unroll.
__global__ __launch_bounds__(256) void agg_kernel(const unsigned short* __restrict__ hb,
                                                  const int* __restrict__ row_ptr,
                                                  const int* __restrict__ col,
                                                  const float* __restrict__ inv_deg,
                                                  float* __restrict__ out, int n) {
    int node = blockIdx.x * 4 + (threadIdx.x >> 6);
    if (node >= n) return;
    int lane = threadIdx.x & 63;
    int slot = lane >> 4, sub = lane & 15;
    int beg = row_ptr[node], end = row_ptr[node + 1];
    const unsigned short* base = hb + (sub << 3);
    float acc[8];
#pragma unroll
    for (int j = 0; j < 8; ++j) acc[j] = 0.f;

    int e = beg + slot;
    for (; e + 4 < end; e += 8) {
        int j0 = col[e];
        int j1 = col[e + 4];
        uint4 v0 = *(const uint4*)(base + ((size_t)j0 << 7));
        uint4 v1 = *(const uint4*)(base + ((size_t)j1 << 7));
        unsigned w0[4] = {v0.x, v0.y, v0.z, v0.w};
        unsigned w1[4] = {v1.x, v1.y, v1.z, v1.w};
#pragma unroll
        for (int d = 0; d < 4; ++d) {
            acc[2 * d + 0] += __uint_as_float(w0[d] << 16);
            acc[2 * d + 1] += __uint_as_float(w0[d] & 0xffff0000u);
            acc[2 * d + 0] += __uint_as_float(w1[d] << 16);
            acc[2 * d + 1] += __uint_as_float(w1[d] & 0xffff0000u);
        }
    }
    if (e < end) {
        int j0 = col[e];
        uint4 v0 = *(const uint4*)(base + ((size_t)j0 << 7));
        unsigned w0[4] = {v0.x, v0.y, v0.z, v0.w};
#pragma unroll
        for (int d = 0; d < 4; ++d) {
            acc[2 * d + 0] += __uint_as_float(w0[d] << 16);
            acc[2 * d + 1] += __uint_as_float(w0[d] & 0xffff0000u);
        }
    }
#pragma unroll
    for (int j = 0; j < 8; ++j) {
        acc[j] += __shfl_xor(acc[j], 16, 64);
        acc[j] += __shfl_xor(acc[j], 32, 64);
    }
    if (slot == 0) {
        float s = inv_deg[node];
        float* op = out + ((size_t)node << 7) + (sub << 3);
        float4 r0, r1;
        r0.x = acc[0] * s; r0.y = acc[1] * s; r0.z = acc[2] * s; r0.w = acc[3] * s;
        r1.x = acc[4] * s; r1.y = acc[5] * s; r1.z = acc[6] * s; r1.w = acc[7] * s;
        *(float4*)op = r0;
        *(float4*)(op + 4) = r1;
    }
}

// ---------------- fused dual GEMM via split-bf16 MFMA (+ optional fused FC) --
// If Wfc != null: instead of storing the 128-wide hidden row, immediately
// reduce it against Wfc (128x2) and write the 2 logits (h2 never materialized).
__global__ __launch_bounds__(256) void gemm_mfma(const float* __restrict__ A0,
                                                 const float* __restrict__ A1,
                                                 const short* __restrict__ Wf0,
                                                 const short* __restrict__ Wf1,
                                                 const float* __restrict__ bias,
                                                 float* __restrict__ out,
                                                 unsigned short* __restrict__ outb,
                                                 const float* __restrict__ Wfc,
                                                 const float* __restrict__ bfc,
                                                 float* __restrict__ fcout,
                                                 int n, int relu) {
    int lane = threadIdx.x & 63;
    int wave = threadIdx.x >> 6;
    int quad = lane >> 4, m16 = lane & 15;
    int row_base = blockIdx.x * 64 + wave * 16;
    int arow = row_base + m16;
    if (arow > n - 1) arow = n - 1;            // clamp (padding rows never stored)

    f32x4 acc[8];
#pragma unroll
    for (int nt = 0; nt < 8; ++nt) acc[nt] = (f32x4){0.f, 0.f, 0.f, 0.f};

#pragma unroll
    for (int pass = 0; pass < 2; ++pass) {
        const float* A = pass ? A1 : A0;
        const short* Wf = pass ? Wf1 : Wf0;
        const float* ap = A + ((size_t)arow << 7) + (quad << 3);
#pragma unroll
        for (int kc = 0; kc < 4; ++kc) {
            float4 av0 = *(const float4*)(ap + kc * 32);
            float4 av1 = *(const float4*)(ap + kc * 32 + 4);
            float af[8] = {av0.x, av0.y, av0.z, av0.w, av1.x, av1.y, av1.z, av1.w};
            short8 ah, al;
#pragma unroll
            for (int j = 0; j < 8; ++j) {
                unsigned short h = bf16_rne(af[j]);
                ah[j] = (short)h;
                al[j] = (short)bf16_rne(af[j] - bf16_to_f32(h));
            }
            const short* wp = Wf + ((size_t)kc * 2 * 64 + lane) * 8;
#pragma unroll
            for (int nt = 0; nt < 8; ++nt) {
                short8 bh = *(const short8*)(wp + (size_t)nt * 4096);
                short8 bl = *(const short8*)(wp + (size_t)nt * 4096 + 512);
                acc[nt] = __builtin_amdgcn_mfma_f32_16x16x32_bf16(ah, bh, acc[nt], 0, 0, 0);
                acc[nt] = __builtin_amdgcn_mfma_f32_16x16x32_bf16(al, bh, acc[nt], 0, 0, 0);
                acc[nt] = __builtin_amdgcn_mfma_f32_16x16x32_bf16(ah, bl, acc[nt], 0, 0, 0);
            }
        }
    }

    // epilogue: C/D layout col = lane&15, row = quad*4 + reg
    float bcol[8];
#pragma unroll
    for (int nt = 0; nt < 8; ++nt) bcol[nt] = bias[nt * 16 + m16];

    if (Wfc) {
        // fused final FC: lane holds cols nt*16+m16; reduce over 16 m16-lanes
        float w0[8], w1[8];
#pragma unroll
        for (int nt = 0; nt < 8; ++nt) {
            float2 wv = *(const float2*)(Wfc + 2 * (nt * 16 + m16));
            w0[nt] = wv.x;
            w1[nt] = wv.y;
        }
        float b0 = bfc[0], b1 = bfc[1];
#pragma unroll
        for (int r = 0; r < 4; ++r) {
            float p0 = 0.f, p1 = 0.f;
#pragma unroll
            for (int nt = 0; nt < 8; ++nt) {
                float v = fmaxf(acc[nt][r] + bcol[nt], 0.f);   // relu (layer2)
                p0 += v * w0[nt];
                p1 += v * w1[nt];
            }
#pragma unroll
            for (int off = 1; off < 16; off <<= 1) {
                p0 += __shfl_xor(p0, off, 64);
                p1 += __shfl_xor(p1, off, 64);
            }
            int row = row_base + quad * 4 + r;
            if (m16 == 0 && row < n) {
                float2 o;
                o.x = p0 + b0;
                o.y = p1 + b1;
                *(float2*)(fcout + 2 * (size_t)row) = o;
            }
        }
    } else {
#pragma unroll
        for (int r = 0; r < 4; ++r) {
            int row = row_base + quad * 4 + r;
            if (row >= n) continue;
            float* op = out + ((size_t)row << 7) + m16;
            unsigned short* opb = outb + ((size_t)row << 7) + m16;
#pragma unroll
            for (int nt = 0; nt < 8; ++nt) {
                float v = acc[nt][r] + bcol[nt];
                if (relu) v = fmaxf(v, 0.f);
                op[nt * 16] = v;
                opb[nt * 16] = bf16_rne(v);
            }
        }
    }
}

extern "C" void kernel_launch(void* const* d_in, const int* in_sizes, int n_in,
                              void* d_out, int out_size, void* d_ws, size_t ws_size,
                              hipStream_t stream) {
    const float* x   = (const float*)d_in[0];
    const int* edge  = (const int*)d_in[1];
    const float* W1l = (const float*)d_in[2];
    const float* W1r = (const float*)d_in[3];
    const float* b1  = (const float*)d_in[4];
    const float* W2l = (const float*)d_in[5];
    const float* W2r = (const float*)d_in[6];
    const float* b2  = (const float*)d_in[7];
    const float* Wfc = (const float*)d_in[8];
    const float* bfc = (const float*)d_in[9];
    float* out = (float*)d_out;

    const int n = NN, ne = NE;
    const int* src = edge;        // edge_index[0]
    const int* dst = edge + ne;   // edge_index[1]

    char* ws = (char*)d_ws;
    size_t off = 0;
    auto alloc = [&](size_t bytes) -> char* {
        char* p = ws + off;
        off = (off + bytes + 511) & ~(size_t)511;
        return p;
    };
    int* deg      = (int*)alloc((size_t)n * 4);
    int* row_ptr  = (int*)alloc((size_t)(n + 1) * 4);
    int* cursor   = (int*)alloc((size_t)n * 4);
    float* invdeg = (float*)alloc((size_t)n * 4);
    int* flags    = (int*)alloc((size_t)SCAN_NB * 4);
    short* wf     = (short*)alloc((size_t)4 * 32768 * 2);
    int* col      = (int*)alloc((size_t)ne * 4);
    float* agg    = (float*)alloc((size_t)n * 128 * 4);
    float* h1     = (float*)alloc((size_t)n * 128 * 4);
    unsigned short* xb  = (unsigned short*)alloc((size_t)n * 128 * 2);
    unsigned short* h1b = (unsigned short*)alloc((size_t)n * 128 * 2);
    (void)ws_size; (void)in_sizes; (void)n_in; (void)out_size;

    setup_kernel<<<SETUP_GRID, 256, 0, stream>>>(x, xb, W1l, W1r, W2l, W2r, wf, deg, flags);
    hist_kernel<<<(ne + 255) / 256, 256, 0, stream>>>(dst, deg, ne);
    scan_chain_kernel<<<SCAN_NB, SCAN_B, 0, stream>>>(deg, row_ptr, cursor, invdeg, flags, n, ne);
    fill_kernel<<<(ne + 255) / 256, 256, 0, stream>>>(src, dst, cursor, col, ne);

    agg_kernel<<<(n + 3) / 4, 256, 0, stream>>>(xb, row_ptr, col, invdeg, agg, n);
    gemm_mfma<<<(n + 63) / 64, 256, 0, stream>>>(agg, x, wf, wf + 32768, b1, h1, h1b,
                                                 (const float*)0, (const float*)0, (float*)0, n, 1);
    agg_kernel<<<(n + 3) / 4, 256, 0, stream>>>(h1b, row_ptr, col, invdeg, agg, n);
    gemm_mfma<<<(n + 63) / 64, 256, 0, stream>>>(agg, h1, wf + 2 * 32768, wf + 3 * 32768, b2,
                                                 (float*)0, (unsigned short*)0, Wfc, bfc, out, n, 1);
}

// Round 8
// 294.116 us; speedup vs baseline: 1.4047x; 1.4047x over previous
//
#include <hip/hip_runtime.h>

#define NN 50000
#define NE 800000
#define SCAN_B 256
#define SCAN_NB ((NN + SCAN_B - 1) / SCAN_B)   // 196

// setup kernel block partition
#define CVT_BLKS 6250                          // NN*128/4/256 exactly
#define PREP_BLKS 32
#define ZERO_BLKS 49                           // NN/4/256 rounded up
#define SETUP_GRID (CVT_BLKS + PREP_BLKS + ZERO_BLKS)

typedef short short8 __attribute__((ext_vector_type(8)));
typedef short short4v __attribute__((ext_vector_type(4)));
typedef float f32x4 __attribute__((ext_vector_type(4)));

__device__ inline unsigned short bf16_rne(float f) {
    unsigned u = __float_as_uint(f);
    unsigned r = (u + 0x7fffu + ((u >> 16) & 1u)) >> 16;
    return (unsigned short)r;
}
__device__ inline float bf16_to_f32(unsigned short h) {
    return __uint_as_float((unsigned)h << 16);
}

// ---------------- fused setup: cvt x->bf16 | weight prep | zero deg ----------
__global__ __launch_bounds__(256) void setup_kernel(const float* __restrict__ x,
                                                    unsigned short* __restrict__ xb,
                                                    const float* __restrict__ W0,
                                                    const float* __restrict__ W1,
                                                    const float* __restrict__ W2,
                                                    const float* __restrict__ W3,
                                                    short* __restrict__ wf,
                                                    int* __restrict__ deg) {
    int b = blockIdx.x;
    if (b < CVT_BLKS) {                       // x -> bf16 (one float4/thread, exact)
        int i = b * 256 + threadIdx.x;
        float4 v = ((const float4*)x)[i];
        short4v r;
        r[0] = (short)bf16_rne(v.x);
        r[1] = (short)bf16_rne(v.y);
        r[2] = (short)bf16_rne(v.z);
        r[3] = (short)bf16_rne(v.w);
        ((short4v*)xb)[i] = r;
    } else if (b < CVT_BLKS + PREP_BLKS) {    // weight split+fragment reorder
        int t = (b - CVT_BLKS) * 256 + threadIdx.x;   // 0..8191
        int mat = t >> 11;
        const float* W = (mat == 0) ? W0 : (mat == 1) ? W1 : (mat == 2) ? W2 : W3;
        short* out = wf + (size_t)mat * 32768;
        int r = t & 2047;
        int nt = r >> 8;
        int kc = (r >> 6) & 3;
        int lane = r & 63;
        int n = nt * 16 + (lane & 15);
        int kbase = kc * 32 + ((lane >> 4) << 3);
        short8 vh, vl;
#pragma unroll
        for (int j = 0; j < 8; ++j) {
            float w = W[(size_t)(kbase + j) * 128 + n];
            unsigned short h = bf16_rne(w);
            unsigned short l = bf16_rne(w - bf16_to_f32(h));
            vh[j] = (short)h;
            vl[j] = (short)l;
        }
        size_t o = ((((size_t)nt * 4 + kc) * 2) * 64 + lane) * 8;
        *(short8*)(out + o) = vh;
        *(short8*)(out + o + 512) = vl;
    } else {                                  // zero deg (int4)
        int i = (b - CVT_BLKS - PREP_BLKS) * 256 + threadIdx.x;
        if (i < NN / 4) ((int4*)deg)[i] = make_int4(0, 0, 0, 0);
    }
}

// ---------------- CSR build ----------------
__global__ void hist_kernel(const int* __restrict__ dst, int* __restrict__ deg, int ne) {
    int e = blockIdx.x * blockDim.x + threadIdx.x;
    if (e < ne) atomicAdd(&deg[dst[e]], 1);
}

__global__ __launch_bounds__(SCAN_B) void block_sum_kernel(const int* __restrict__ deg,
                                                           int* __restrict__ bsum, int n) {
    __shared__ int s[SCAN_B];
    int i = blockIdx.x * SCAN_B + threadIdx.x;
    int v = (i < n) ? deg[i] : 0;
    s[threadIdx.x] = v;
    __syncthreads();
    for (int d = SCAN_B >> 1; d > 0; d >>= 1) {
        if (threadIdx.x < d) s[threadIdx.x] += s[threadIdx.x + d];
        __syncthreads();
    }
    if (threadIdx.x == 0) bsum[blockIdx.x] = s[0];
}

__global__ __launch_bounds__(SCAN_B) void scan_bsums_kernel(int* __restrict__ bsum, int nb) {
    __shared__ int s[SCAN_B];
    int t = threadIdx.x;
    s[t] = (t < nb) ? bsum[t] : 0;
    __syncthreads();
    for (int d = 1; d < SCAN_B; d <<= 1) {
        int v = (t >= d) ? s[t - d] : 0;
        __syncthreads();
        s[t] += v;
        __syncthreads();
    }
    if (t < nb) bsum[t] = s[t];   // inclusive
}

__global__ __launch_bounds__(SCAN_B) void scatter_scan_kernel(const int* __restrict__ deg,
                                                              const int* __restrict__ bsum,
                                                              int* __restrict__ row_ptr,
                                                              int* __restrict__ cursor,
                                                              float* __restrict__ inv_deg,
                                                              int n, int ne) {
    __shared__ int s[SCAN_B];
    int t = threadIdx.x;
    int i = blockIdx.x * SCAN_B + t;
    int v = (i < n) ? deg[i] : 0;
    s[t] = v;
    __syncthreads();
    for (int d = 1; d < SCAN_B; d <<= 1) {
        int u = (t >= d) ? s[t - d] : 0;
        __syncthreads();
        s[t] += u;
        __syncthreads();
    }
    int base = (blockIdx.x == 0) ? 0 : bsum[blockIdx.x - 1];
    if (i < n) {
        int rp = base + s[t] - v;   // exclusive
        row_ptr[i] = rp;
        cursor[i] = rp;
        inv_deg[i] = 1.0f / (float)(v > 0 ? v : 1);
    }
    if (blockIdx.x == 0 && t == 0) row_ptr[n] = ne;
}

__global__ void fill_kernel(const int* __restrict__ src, const int* __restrict__ dst,
                            int* __restrict__ cursor, int* __restrict__ col, int ne) {
    int e = blockIdx.x * blockDim.x + threadIdx.x;
    if (e >= ne) return;
    int d = dst[e];
    int pos = atomicAdd(&cursor[d], 1);
    col[pos] = src[e];
}

// ---------------- mean aggregation over bf16 features, fp32 accumulate ------
// one wave per node; slot = lane>>4 handles edge e = beg + i*4 + slot, sub =
// lane&15 handles features [sub*8, sub*8+8). 16B/lane loads, x2 unroll.
__global__ __launch_bounds__(256) void agg_kernel(const unsigned short* __restrict__ hb,
                                                  const int* __restrict__ row_ptr,
                                                  const int* __restrict__ col,
                                                  const float* __restrict__ inv_deg,
                                                  float* __restrict__ out, int n) {
    int node = blockIdx.x * 4 + (threadIdx.x >> 6);
    if (node >= n) return;
    int lane = threadIdx.x & 63;
    int slot = lane >> 4, sub = lane & 15;
    int beg = row_ptr[node], end = row_ptr[node + 1];
    const unsigned short* base = hb + (sub << 3);
    float acc[8];
#pragma unroll
    for (int j = 0; j < 8; ++j) acc[j] = 0.f;

    int e = beg + slot;
    for (; e + 4 < end; e += 8) {
        int j0 = col[e];
        int j1 = col[e + 4];
        uint4 v0 = *(const uint4*)(base + ((size_t)j0 << 7));
        uint4 v1 = *(const uint4*)(base + ((size_t)j1 << 7));
        unsigned w0[4] = {v0.x, v0.y, v0.z, v0.w};
        unsigned w1[4] = {v1.x, v1.y, v1.z, v1.w};
#pragma unroll
        for (int d = 0; d < 4; ++d) {
            acc[2 * d + 0] += __uint_as_float(w0[d] << 16);
            acc[2 * d + 1] += __uint_as_float(w0[d] & 0xffff0000u);
            acc[2 * d + 0] += __uint_as_float(w1[d] << 16);
            acc[2 * d + 1] += __uint_as_float(w1[d] & 0xffff0000u);
        }
    }
    if (e < end) {
        int j0 = col[e];
        uint4 v0 = *(const uint4*)(base + ((size_t)j0 << 7));
        unsigned w0[4] = {v0.x, v0.y, v0.z, v0.w};
#pragma unroll
        for (int d = 0; d < 4; ++d) {
            acc[2 * d + 0] += __uint_as_float(w0[d] << 16);
            acc[2 * d + 1] += __uint_as_float(w0[d] & 0xffff0000u);
        }
    }
#pragma unroll
    for (int j = 0; j < 8; ++j) {
        acc[j] += __shfl_xor(acc[j], 16, 64);
        acc[j] += __shfl_xor(acc[j], 32, 64);
    }
    if (slot == 0) {
        float s = inv_deg[node];
        float* op = out + ((size_t)node << 7) + (sub << 3);
        float4 r0, r1;
        r0.x = acc[0] * s; r0.y = acc[1] * s; r0.z = acc[2] * s; r0.w = acc[3] * s;
        r1.x = acc[4] * s; r1.y = acc[5] * s; r1.z = acc[6] * s; r1.w = acc[7] * s;
        *(float4*)op = r0;
        *(float4*)(op + 4) = r1;
    }
}

// ---------------- fused dual GEMM via split-bf16 MFMA (+ optional fused FC) --
__global__ __launch_bounds__(256) void gemm_mfma(const float* __restrict__ A0,
                                                 const float* __restrict__ A1,
                                                 const short* __restrict__ Wf0,
                                                 const short* __restrict__ Wf1,
                                                 const float* __restrict__ bias,
                                                 float* __restrict__ out,
                                                 unsigned short* __restrict__ outb,
                                                 const float* __restrict__ Wfc,
                                                 const float* __restrict__ bfc,
                                                 float* __restrict__ fcout,
                                                 int n, int relu) {
    int lane = threadIdx.x & 63;
    int wave = threadIdx.x >> 6;
    int quad = lane >> 4, m16 = lane & 15;
    int row_base = blockIdx.x * 64 + wave * 16;
    int arow = row_base + m16;
    if (arow > n - 1) arow = n - 1;            // clamp (padding rows never stored)

    f32x4 acc[8];
#pragma unroll
    for (int nt = 0; nt < 8; ++nt) acc[nt] = (f32x4){0.f, 0.f, 0.f, 0.f};

#pragma unroll
    for (int pass = 0; pass < 2; ++pass) {
        const float* A = pass ? A1 : A0;
        const short* Wf = pass ? Wf1 : Wf0;
        const float* ap = A + ((size_t)arow << 7) + (quad << 3);
#pragma unroll
        for (int kc = 0; kc < 4; ++kc) {
            float4 av0 = *(const float4*)(ap + kc * 32);
            float4 av1 = *(const float4*)(ap + kc * 32 + 4);
            float af[8] = {av0.x, av0.y, av0.z, av0.w, av1.x, av1.y, av1.z, av1.w};
            short8 ah, al;
#pragma unroll
            for (int j = 0; j < 8; ++j) {
                unsigned short h = bf16_rne(af[j]);
                ah[j] = (short)h;
                al[j] = (short)bf16_rne(af[j] - bf16_to_f32(h));
            }
            const short* wp = Wf + ((size_t)kc * 2 * 64 + lane) * 8;
#pragma unroll
            for (int nt = 0; nt < 8; ++nt) {
                short8 bh = *(const short8*)(wp + (size_t)nt * 4096);
                short8 bl = *(const short8*)(wp + (size_t)nt * 4096 + 512);
                acc[nt] = __builtin_amdgcn_mfma_f32_16x16x32_bf16(ah, bh, acc[nt], 0, 0, 0);
                acc[nt] = __builtin_amdgcn_mfma_f32_16x16x32_bf16(al, bh, acc[nt], 0, 0, 0);
                acc[nt] = __builtin_amdgcn_mfma_f32_16x16x32_bf16(ah, bl, acc[nt], 0, 0, 0);
            }
        }
    }

    // epilogue: C/D layout col = lane&15, row = quad*4 + reg
    float bcol[8];
#pragma unroll
    for (int nt = 0; nt < 8; ++nt) bcol[nt] = bias[nt * 16 + m16];

    if (Wfc) {
        // fused final FC: lane holds cols nt*16+m16; reduce over 16 m16-lanes
        float w0[8], w1[8];
#pragma unroll
        for (int nt = 0; nt < 8; ++nt) {
            float2 wv = *(const float2*)(Wfc + 2 * (nt * 16 + m16));
            w0[nt] = wv.x;
            w1[nt] = wv.y;
        }
        float b0 = bfc[0], b1 = bfc[1];
#pragma unroll
        for (int r = 0; r < 4; ++r) {
            float p0 = 0.f, p1 = 0.f;
#pragma unroll
            for (int nt = 0; nt < 8; ++nt) {
                float v = fmaxf(acc[nt][r] + bcol[nt], 0.f);   // relu (layer2)
                p0 += v * w0[nt];
                p1 += v * w1[nt];
            }
#pragma unroll
            for (int off = 1; off < 16; off <<= 1) {
                p0 += __shfl_xor(p0, off, 64);
                p1 += __shfl_xor(p1, off, 64);
            }
            int row = row_base + quad * 4 + r;
            if (m16 == 0 && row < n) {
                float2 o;
                o.x = p0 + b0;
                o.y = p1 + b1;
                *(float2*)(fcout + 2 * (size_t)row) = o;
            }
        }
    } else {
#pragma unroll
        for (int r = 0; r < 4; ++r) {
            int row = row_base + quad * 4 + r;
            if (row >= n) continue;
            float* op = out + ((size_t)row << 7) + m16;
            unsigned short* opb = outb + ((size_t)row << 7) + m16;
#pragma unroll
            for (int nt = 0; nt < 8; ++nt) {
                float v = acc[nt][r] + bcol[nt];
                if (relu) v = fmaxf(v, 0.f);
                op[nt * 16] = v;
                opb[nt * 16] = bf16_rne(v);
            }
        }
    }
}

extern "C" void kernel_launch(void* const* d_in, const int* in_sizes, int n_in,
                              void* d_out, int out_size, void* d_ws, size_t ws_size,
                              hipStream_t stream) {
    const float* x   = (const float*)d_in[0];
    const int* edge  = (const int*)d_in[1];
    const float* W1l = (const float*)d_in[2];
    const float* W1r = (const float*)d_in[3];
    const float* b1  = (const float*)d_in[4];
    const float* W2l = (const float*)d_in[5];
    const float* W2r = (const float*)d_in[6];
    const float* b2  = (const float*)d_in[7];
    const float* Wfc = (const float*)d_in[8];
    const float* bfc = (const float*)d_in[9];
    float* out = (float*)d_out;

    const int n = NN, ne = NE;
    const int* src = edge;        // edge_index[0]
    const int* dst = edge + ne;   // edge_index[1]

    char* ws = (char*)d_ws;
    size_t off = 0;
    auto alloc = [&](size_t bytes) -> char* {
        char* p = ws + off;
        off = (off + bytes + 511) & ~(size_t)511;
        return p;
    };
    int* deg      = (int*)alloc((size_t)n * 4);
    int* row_ptr  = (int*)alloc((size_t)(n + 1) * 4);
    int* cursor   = (int*)alloc((size_t)n * 4);
    float* invdeg = (float*)alloc((size_t)n * 4);
    int* bsum     = (int*)alloc((size_t)SCAN_NB * 4);
    short* wf     = (short*)alloc((size_t)4 * 32768 * 2);
    int* col      = (int*)alloc((size_t)ne * 4);
    float* agg    = (float*)alloc((size_t)n * 128 * 4);
    float* h1     = (float*)alloc((size_t)n * 128 * 4);
    unsigned short* xb  = (unsigned short*)alloc((size_t)n * 128 * 2);
    unsigned short* h1b = (unsigned short*)alloc((size_t)n * 128 * 2);
    (void)ws_size; (void)in_sizes; (void)n_in; (void)out_size;

    setup_kernel<<<SETUP_GRID, 256, 0, stream>>>(x, xb, W1l, W1r, W2l, W2r, wf, deg);
    hist_kernel<<<(ne + 255) / 256, 256, 0, stream>>>(dst, deg, ne);
    block_sum_kernel<<<SCAN_NB, SCAN_B, 0, stream>>>(deg, bsum, n);
    scan_bsums_kernel<<<1, SCAN_B, 0, stream>>>(bsum, SCAN_NB);
    scatter_scan_kernel<<<SCAN_NB, SCAN_B, 0, stream>>>(deg, bsum, row_ptr, cursor, invdeg, n, ne);
    fill_kernel<<<(ne + 255) / 256, 256, 0, stream>>>(src, dst, cursor, col, ne);

    agg_kernel<<<(n + 3) / 4, 256, 0, stream>>>(xb, row_ptr, col, invdeg, agg, n);
    gemm_mfma<<<(n + 63) / 64, 256, 0, stream>>>(agg, x, wf, wf + 32768, b1, h1, h1b,
                                                 (const float*)0, (const float*)0, (float*)0, n, 1);
    agg_kernel<<<(n + 3) / 4, 256, 0, stream>>>(h1b, row_ptr, col, invdeg, agg, n);
    gemm_mfma<<<(n + 63) / 64, 256, 0, stream>>>(agg, h1, wf + 2 * 32768, wf + 3 * 32768, b2,
                                                 (float*)0, (unsigned short*)0, Wfc, bfc, out, n, 1);
}

// Round 9
// 269.250 us; speedup vs baseline: 1.5344x; 1.0924x over previous
//
#include <hip/hip_runtime.h>

#define NN 50000
#define NE 800000
#define NB_BUCKET 49                           // ceil(NN/1024)
#define EPB 2048                               // edges per block (hist/binA)
#define NBLK_E ((NE + EPB - 1) / EPB)          // 391

// setup kernel block partition
#define CVT_BLKS 6250                          // NN*128/4/256 exactly
#define PREP_BLKS 32
#define SETUP_GRID (CVT_BLKS + PREP_BLKS + NBLK_E)

typedef short short8 __attribute__((ext_vector_type(8)));
typedef short short4v __attribute__((ext_vector_type(4)));
typedef float f32x4 __attribute__((ext_vector_type(4)));

__device__ inline unsigned short bf16_rne(float f) {
    unsigned u = __float_as_uint(f);
    unsigned r = (u + 0x7fffu + ((u >> 16) & 1u)) >> 16;
    return (unsigned short)r;
}
__device__ inline float bf16_to_f32(unsigned short h) {
    return __uint_as_float((unsigned)h << 16);
}

// ---- fused setup: cvt x->bf16 | weight prep | per-block bucket histograms ---
__global__ __launch_bounds__(256) void setup_kernel(const float* __restrict__ x,
                                                    unsigned short* __restrict__ xb,
                                                    const float* __restrict__ W0,
                                                    const float* __restrict__ W1,
                                                    const float* __restrict__ W2,
                                                    const float* __restrict__ W3,
                                                    short* __restrict__ wf,
                                                    const int* __restrict__ dst,
                                                    int* __restrict__ bhp, int ne) {
    int b = blockIdx.x;
    if (b < CVT_BLKS) {                       // x -> bf16 (one float4/thread, exact)
        int i = b * 256 + threadIdx.x;
        float4 v = ((const float4*)x)[i];
        short4v r;
        r[0] = (short)bf16_rne(v.x);
        r[1] = (short)bf16_rne(v.y);
        r[2] = (short)bf16_rne(v.z);
        r[3] = (short)bf16_rne(v.w);
        ((short4v*)xb)[i] = r;
    } else if (b < CVT_BLKS + PREP_BLKS) {    // weight split+fragment reorder
        int t = (b - CVT_BLKS) * 256 + threadIdx.x;   // 0..8191
        int mat = t >> 11;
        const float* W = (mat == 0) ? W0 : (mat == 1) ? W1 : (mat == 2) ? W2 : W3;
        short* out = wf + (size_t)mat * 32768;
        int r = t & 2047;
        int nt = r >> 8;
        int kc = (r >> 6) & 3;
        int lane = r & 63;
        int n = nt * 16 + (lane & 15);
        int kbase = kc * 32 + ((lane >> 4) << 3);
        short8 vh, vl;
#pragma unroll
        for (int j = 0; j < 8; ++j) {
            float w = W[(size_t)(kbase + j) * 128 + n];
            unsigned short h = bf16_rne(w);
            unsigned short l = bf16_rne(w - bf16_to_f32(h));
            vh[j] = (short)h;
            vl[j] = (short)l;
        }
        size_t o = ((((size_t)nt * 4 + kc) * 2) * 64 + lane) * 8;
        *(short8*)(out + o) = vh;
        *(short8*)(out + o + 512) = vl;
    } else {                                  // per-block bucket histogram (partials)
        __shared__ int cnt[NB_BUCKET];
        int blk = b - CVT_BLKS - PREP_BLKS;
        int t = threadIdx.x;
        if (t < NB_BUCKET) cnt[t] = 0;
        __syncthreads();
        int base = blk * EPB + t * 8;
        int d[8];
        int m = 0;
        if (base + 8 <= ne) {
            *(int4*)&d[0] = *(const int4*)(dst + base);
            *(int4*)&d[4] = *(const int4*)(dst + base + 4);
            m = 8;
        } else if (base < ne) {
            m = ne - base;
            for (int i = 0; i < m; ++i) d[i] = dst[base + i];
        }
        for (int i = 0; i < m; ++i) atomicAdd(&cnt[d[i] >> 10], 1);
        __syncthreads();
        if (t < NB_BUCKET) bhp[blk * NB_BUCKET + t] = cnt[t];
    }
}

// ---- sum partials + scan 49 buckets (single wave) ---------------------------
__global__ __launch_bounds__(64) void bucket_scan_kernel(const int* __restrict__ bhp,
                                                         int* __restrict__ bucketOff,
                                                         int* __restrict__ cursorA,
                                                         int* __restrict__ row_ptr) {
    int t = threadIdx.x;
    int v = 0;
    if (t < NB_BUCKET)
        for (int i = 0; i < NBLK_E; ++i) v += bhp[i * NB_BUCKET + t];
    int incl = v;
#pragma unroll
    for (int d = 1; d < 64; d <<= 1) {
        int p = __shfl_up(incl, d, 64);
        if (t >= d) incl += p;
    }
    if (t < NB_BUCKET) {
        bucketOff[t] = incl - v;
        cursorA[t] = incl - v;
    }
    if (t == NB_BUCKET - 1) bucketOff[NB_BUCKET] = incl;   // = NE
    if (t == 63) row_ptr[NN] = NE;
}

// ---- phase A: bin edges into bucket regions as packed (dst_local<<16)|src ---
__global__ __launch_bounds__(256) void binA_kernel(const int* __restrict__ src,
                                                   const int* __restrict__ dst,
                                                   int* __restrict__ cursorA,
                                                   unsigned* __restrict__ packed, int ne) {
    __shared__ int cnt[NB_BUCKET];
    __shared__ int gstart[NB_BUCKET];
    __shared__ int cur[NB_BUCKET];
    int t = threadIdx.x;
    if (t < NB_BUCKET) cnt[t] = 0;
    __syncthreads();
    int base = blockIdx.x * EPB + t * 8;
    int s[8], d[8];
    int m = 0;
    if (base + 8 <= ne) {
        *(int4*)&s[0] = *(const int4*)(src + base);
        *(int4*)&s[4] = *(const int4*)(src + base + 4);
        *(int4*)&d[0] = *(const int4*)(dst + base);
        *(int4*)&d[4] = *(const int4*)(dst + base + 4);
        m = 8;
    } else if (base < ne) {
        m = ne - base;
        for (int i = 0; i < m; ++i) { s[i] = src[base + i]; d[i] = dst[base + i]; }
    }
    for (int i = 0; i < m; ++i) atomicAdd(&cnt[d[i] >> 10], 1);
    __syncthreads();
    if (t < NB_BUCKET) {
        gstart[t] = atomicAdd(&cursorA[t], cnt[t]);
        cur[t] = 0;
    }
    __syncthreads();
    for (int i = 0; i < m; ++i) {
        int b = d[i] >> 10;
        int l = atomicAdd(&cur[b], 1);
        packed[gstart[b] + l] = ((unsigned)(d[i] & 1023) << 16) | (unsigned)s[i];
    }
}

// ---- phase B: one block per bucket; LDS deg+scan -> row_ptr/inv_deg/col -----
// All col writes for a bucket come from ONE block into a contiguous ~65KB
// region -> no cross-XCD line sharing, no write amplification.
__global__ __launch_bounds__(1024) void binB_kernel(const unsigned* __restrict__ packed,
                                                    const int* __restrict__ bucketOff,
                                                    int* __restrict__ row_ptr,
                                                    float* __restrict__ inv_deg,
                                                    int* __restrict__ col, int n) {
    __shared__ int sdeg[1024];
    __shared__ int scur[1024];
    int b = blockIdx.x, t = threadIdx.x;
    int ebeg = bucketOff[b], eend = bucketOff[b + 1];
    int nbeg = b << 10;
    int cnt = n - nbeg;
    if (cnt > 1024) cnt = 1024;
    sdeg[t] = 0;
    __syncthreads();
    for (int e = ebeg + t; e < eend; e += 1024) atomicAdd(&sdeg[packed[e] >> 16], 1);
    __syncthreads();
    int v = sdeg[t];
    for (int d = 1; d < 1024; d <<= 1) {       // inclusive scan, double-barrier
        int u = (t >= d) ? sdeg[t - d] : 0;
        __syncthreads();
        sdeg[t] += u;
        __syncthreads();
    }
    int excl = sdeg[t] - v;
    scur[t] = excl;
    if (t < cnt) {
        row_ptr[nbeg + t] = ebeg + excl;
        inv_deg[nbeg + t] = 1.0f / (float)(v > 0 ? v : 1);
    }
    __syncthreads();
    for (int e = ebeg + t; e < eend; e += 1024) {
        unsigned w = packed[e];
        int dl = w >> 16;
        int pos = ebeg + atomicAdd(&scur[dl], 1);
        col[pos] = (int)(w & 0xffffu);
    }
}

// ---------------- mean aggregation over bf16 features, fp32 accumulate ------
__global__ __launch_bounds__(256) void agg_kernel(const unsigned short* __restrict__ hb,
                                                  const int* __restrict__ row_ptr,
                                                  const int* __restrict__ col,
                                                  const float* __restrict__ inv_deg,
                                                  float* __restrict__ out, int n) {
    int node = blockIdx.x * 4 + (threadIdx.x >> 6);
    if (node >= n) return;
    int lane = threadIdx.x & 63;
    int slot = lane >> 4, sub = lane & 15;
    int beg = row_ptr[node], end = row_ptr[node + 1];
    const unsigned short* base = hb + (sub << 3);
    float acc[8];
#pragma unroll
    for (int j = 0; j < 8; ++j) acc[j] = 0.f;

    int e = beg + slot;
    for (; e + 4 < end; e += 8) {
        int j0 = col[e];
        int j1 = col[e + 4];
        uint4 v0 = *(const uint4*)(base + ((size_t)j0 << 7));
        uint4 v1 = *(const uint4*)(base + ((size_t)j1 << 7));
        unsigned w0[4] = {v0.x, v0.y, v0.z, v0.w};
        unsigned w1[4] = {v1.x, v1.y, v1.z, v1.w};
#pragma unroll
        for (int d = 0; d < 4; ++d) {
            acc[2 * d + 0] += __uint_as_float(w0[d] << 16);
            acc[2 * d + 1] += __uint_as_float(w0[d] & 0xffff0000u);
            acc[2 * d + 0] += __uint_as_float(w1[d] << 16);
            acc[2 * d + 1] += __uint_as_float(w1[d] & 0xffff0000u);
        }
    }
    if (e < end) {
        int j0 = col[e];
        uint4 v0 = *(const uint4*)(base + ((size_t)j0 << 7));
        unsigned w0[4] = {v0.x, v0.y, v0.z, v0.w};
#pragma unroll
        for (int d = 0; d < 4; ++d) {
            acc[2 * d + 0] += __uint_as_float(w0[d] << 16);
            acc[2 * d + 1] += __uint_as_float(w0[d] & 0xffff0000u);
        }
    }
#pragma unroll
    for (int j = 0; j < 8; ++j) {
        acc[j] += __shfl_xor(acc[j], 16, 64);
        acc[j] += __shfl_xor(acc[j], 32, 64);
    }
    if (slot == 0) {
        float s = inv_deg[node];
        float* op = out + ((size_t)node << 7) + (sub << 3);
        float4 r0, r1;
        r0.x = acc[0] * s; r0.y = acc[1] * s; r0.z = acc[2] * s; r0.w = acc[3] * s;
        r1.x = acc[4] * s; r1.y = acc[5] * s; r1.z = acc[6] * s; r1.w = acc[7] * s;
        *(float4*)op = r0;
        *(float4*)(op + 4) = r1;
    }
}

// ---------------- fused dual GEMM via split-bf16 MFMA (+ optional fused FC) --
__global__ __launch_bounds__(256) void gemm_mfma(const float* __restrict__ A0,
                                                 const float* __restrict__ A1,
                                                 const short* __restrict__ Wf0,
                                                 const short* __restrict__ Wf1,
                                                 const float* __restrict__ bias,
                                                 float* __restrict__ out,
                                                 unsigned short* __restrict__ outb,
                                                 const float* __restrict__ Wfc,
                                                 const float* __restrict__ bfc,
                                                 float* __restrict__ fcout,
                                                 int n, int relu) {
    int lane = threadIdx.x & 63;
    int wave = threadIdx.x >> 6;
    int quad = lane >> 4, m16 = lane & 15;
    int row_base = blockIdx.x * 64 + wave * 16;
    int arow = row_base + m16;
    if (arow > n - 1) arow = n - 1;            // clamp (padding rows never stored)

    f32x4 acc[8];
#pragma unroll
    for (int nt = 0; nt < 8; ++nt) acc[nt] = (f32x4){0.f, 0.f, 0.f, 0.f};

#pragma unroll
    for (int pass = 0; pass < 2; ++pass) {
        const float* A = pass ? A1 : A0;
        const short* Wf = pass ? Wf1 : Wf0;
        const float* ap = A + ((size_t)arow << 7) + (quad << 3);
#pragma unroll
        for (int kc = 0; kc < 4; ++kc) {
            float4 av0 = *(const float4*)(ap + kc * 32);
            float4 av1 = *(const float4*)(ap + kc * 32 + 4);
            float af[8] = {av0.x, av0.y, av0.z, av0.w, av1.x, av1.y, av1.z, av1.w};
            short8 ah, al;
#pragma unroll
            for (int j = 0; j < 8; ++j) {
                unsigned short h = bf16_rne(af[j]);
                ah[j] = (short)h;
                al[j] = (short)bf16_rne(af[j] - bf16_to_f32(h));
            }
            const short* wp = Wf + ((size_t)kc * 2 * 64 + lane) * 8;
#pragma unroll
            for (int nt = 0; nt < 8; ++nt) {
                short8 bh = *(const short8*)(wp + (size_t)nt * 4096);
                short8 bl = *(const short8*)(wp + (size_t)nt * 4096 + 512);
                acc[nt] = __builtin_amdgcn_mfma_f32_16x16x32_bf16(ah, bh, acc[nt], 0, 0, 0);
                acc[nt] = __builtin_amdgcn_mfma_f32_16x16x32_bf16(al, bh, acc[nt], 0, 0, 0);
                acc[nt] = __builtin_amdgcn_mfma_f32_16x16x32_bf16(ah, bl, acc[nt], 0, 0, 0);
            }
        }
    }

    // epilogue: C/D layout col = lane&15, row = quad*4 + reg
    float bcol[8];
#pragma unroll
    for (int nt = 0; nt < 8; ++nt) bcol[nt] = bias[nt * 16 + m16];

    if (Wfc) {
        // fused final FC: lane holds cols nt*16+m16; reduce over 16 m16-lanes
        float w0[8], w1[8];
#pragma unroll
        for (int nt = 0; nt < 8; ++nt) {
            float2 wv = *(const float2*)(Wfc + 2 * (nt * 16 + m16));
            w0[nt] = wv.x;
            w1[nt] = wv.y;
        }
        float b0 = bfc[0], b1 = bfc[1];
#pragma unroll
        for (int r = 0; r < 4; ++r) {
            float p0 = 0.f, p1 = 0.f;
#pragma unroll
            for (int nt = 0; nt < 8; ++nt) {
                float v = fmaxf(acc[nt][r] + bcol[nt], 0.f);   // relu (layer2)
                p0 += v * w0[nt];
                p1 += v * w1[nt];
            }
#pragma unroll
            for (int off = 1; off < 16; off <<= 1) {
                p0 += __shfl_xor(p0, off, 64);
                p1 += __shfl_xor(p1, off, 64);
            }
            int row = row_base + quad * 4 + r;
            if (m16 == 0 && row < n) {
                float2 o;
                o.x = p0 + b0;
                o.y = p1 + b1;
                *(float2*)(fcout + 2 * (size_t)row) = o;
            }
        }
    } else {
#pragma unroll
        for (int r = 0; r < 4; ++r) {
            int row = row_base + quad * 4 + r;
            if (row >= n) continue;
            float* op = out + ((size_t)row << 7) + m16;
            unsigned short* opb = outb + ((size_t)row << 7) + m16;
#pragma unroll
            for (int nt = 0; nt < 8; ++nt) {
                float v = acc[nt][r] + bcol[nt];
                if (relu) v = fmaxf(v, 0.f);
                op[nt * 16] = v;
                opb[nt * 16] = bf16_rne(v);
            }
        }
    }
}

extern "C" void kernel_launch(void* const* d_in, const int* in_sizes, int n_in,
                              void* d_out, int out_size, void* d_ws, size_t ws_size,
                              hipStream_t stream) {
    const float* x   = (const float*)d_in[0];
    const int* edge  = (const int*)d_in[1];
    const float* W1l = (const float*)d_in[2];
    const float* W1r = (const float*)d_in[3];
    const float* b1  = (const float*)d_in[4];
    const float* W2l = (const float*)d_in[5];
    const float* W2r = (const float*)d_in[6];
    const float* b2  = (const float*)d_in[7];
    const float* Wfc = (const float*)d_in[8];
    const float* bfc = (const float*)d_in[9];
    float* out = (float*)d_out;

    const int n = NN, ne = NE;
    const int* src = edge;        // edge_index[0]
    const int* dst = edge + ne;   // edge_index[1]

    char* ws = (char*)d_ws;
    size_t off = 0;
    auto alloc = [&](size_t bytes) -> char* {
        char* p = ws + off;
        off = (off + bytes + 511) & ~(size_t)511;
        return p;
    };
    int* row_ptr    = (int*)alloc((size_t)(n + 1) * 4);
    float* invdeg   = (float*)alloc((size_t)n * 4);
    int* bucketOff  = (int*)alloc((size_t)(NB_BUCKET + 1) * 4);
    int* cursorA    = (int*)alloc((size_t)NB_BUCKET * 4);
    int* bhp        = (int*)alloc((size_t)NBLK_E * NB_BUCKET * 4);
    short* wf       = (short*)alloc((size_t)4 * 32768 * 2);
    unsigned* packed= (unsigned*)alloc((size_t)ne * 4);
    int* col        = (int*)alloc((size_t)ne * 4);
    float* agg      = (float*)alloc((size_t)n * 128 * 4);
    float* h1       = (float*)alloc((size_t)n * 128 * 4);
    unsigned short* xb  = (unsigned short*)alloc((size_t)n * 128 * 2);
    unsigned short* h1b = (unsigned short*)alloc((size_t)n * 128 * 2);
    (void)ws_size; (void)in_sizes; (void)n_in; (void)out_size;

    setup_kernel<<<SETUP_GRID, 256, 0, stream>>>(x, xb, W1l, W1r, W2l, W2r, wf, dst, bhp, ne);
    bucket_scan_kernel<<<1, 64, 0, stream>>>(bhp, bucketOff, cursorA, row_ptr);
    binA_kernel<<<NBLK_E, 256, 0, stream>>>(src, dst, cursorA, packed, ne);
    binB_kernel<<<NB_BUCKET, 1024, 0, stream>>>(packed, bucketOff, row_ptr, invdeg, col, n);

    agg_kernel<<<(n + 3) / 4, 256, 0, stream>>>(xb, row_ptr, col, invdeg, agg, n);
    gemm_mfma<<<(n + 63) / 64, 256, 0, stream>>>(agg, x, wf, wf + 32768, b1, h1, h1b,
                                                 (const float*)0, (const float*)0, (float*)0, n, 1);
    agg_kernel<<<(n + 3) / 4, 256, 0, stream>>>(h1b, row_ptr, col, invdeg, agg, n);
    gemm_mfma<<<(n + 63) / 64, 256, 0, stream>>>(agg, h1, wf + 2 * 32768, wf + 3 * 32768, b2,
                                                 (float*)0, (unsigned short*)0, Wfc, bfc, out, n, 1);
}

// Round 10
// 227.225 us; speedup vs baseline: 1.8182x; 1.1850x over previous
//
#include <hip/hip_runtime.h>

#define NN 50000
#define NE 800000
#define BSHIFT 9
#define NB_BUCKET ((NN + 511) >> BSHIFT)       // 98
#define BCAP 16384                             // slots per bucket region
#define EPB 2048                               // edges per binA block
#define NBLK_E ((NE + EPB - 1) / EPB)          // 391

// setup kernel block partition
#define CVT_BLKS 6250                          // NN*128/4/256 exactly
#define PREP_BLKS 32
#define SETUP_GRID (CVT_BLKS + PREP_BLKS + 1)

typedef short short8 __attribute__((ext_vector_type(8)));
typedef short short4v __attribute__((ext_vector_type(4)));
typedef float f32x4 __attribute__((ext_vector_type(4)));

__device__ inline unsigned short bf16_rne(float f) {
    unsigned u = __float_as_uint(f);
    unsigned r = (u + 0x7fffu + ((u >> 16) & 1u)) >> 16;
    return (unsigned short)r;
}
__device__ inline float bf16_to_f32(unsigned short h) {
    return __uint_as_float((unsigned)h << 16);
}

// ---- fused setup: cvt x->bf16 | weight prep | zero bucket cursors ----------
__global__ __launch_bounds__(256) void setup_kernel(const float* __restrict__ x,
                                                    unsigned short* __restrict__ xb,
                                                    const float* __restrict__ W0,
                                                    const float* __restrict__ W1,
                                                    const float* __restrict__ W2,
                                                    const float* __restrict__ W3,
                                                    short* __restrict__ wf,
                                                    int* __restrict__ cursor0) {
    int b = blockIdx.x;
    if (b < CVT_BLKS) {                       // x -> bf16 (one float4/thread, exact)
        int i = b * 256 + threadIdx.x;
        float4 v = ((const float4*)x)[i];
        short4v r;
        r[0] = (short)bf16_rne(v.x);
        r[1] = (short)bf16_rne(v.y);
        r[2] = (short)bf16_rne(v.z);
        r[3] = (short)bf16_rne(v.w);
        ((short4v*)xb)[i] = r;
    } else if (b < CVT_BLKS + PREP_BLKS) {    // weight split+fragment reorder
        int t = (b - CVT_BLKS) * 256 + threadIdx.x;   // 0..8191
        int mat = t >> 11;
        const float* W = (mat == 0) ? W0 : (mat == 1) ? W1 : (mat == 2) ? W2 : W3;
        short* out = wf + (size_t)mat * 32768;
        int r = t & 2047;
        int nt = r >> 8;
        int kc = (r >> 6) & 3;
        int lane = r & 63;
        int n = nt * 16 + (lane & 15);
        int kbase = kc * 32 + ((lane >> 4) << 3);
        short8 vh, vl;
#pragma unroll
        for (int j = 0; j < 8; ++j) {
            float w = W[(size_t)(kbase + j) * 128 + n];
            unsigned short h = bf16_rne(w);
            unsigned short l = bf16_rne(w - bf16_to_f32(h));
            vh[j] = (short)h;
            vl[j] = (short)l;
        }
        size_t o = ((((size_t)nt * 4 + kc) * 2) * 64 + lane) * 8;
        *(short8*)(out + o) = vh;
        *(short8*)(out + o + 512) = vl;
    } else {                                  // zero bucket cursors
        if (threadIdx.x < NB_BUCKET) cursor0[threadIdx.x] = 0;
    }
}

// ---- phase A: bin edges into fixed bucket regions, packed (dl<<16)|src -----
__global__ __launch_bounds__(256) void binA_kernel(const int* __restrict__ src,
                                                   const int* __restrict__ dst,
                                                   int* __restrict__ cursor0,
                                                   unsigned* __restrict__ packed, int ne) {
    __shared__ int cnt[NB_BUCKET];
    __shared__ int gstart[NB_BUCKET];
    __shared__ int cur[NB_BUCKET];
    int t = threadIdx.x;
    if (t < NB_BUCKET) cnt[t] = 0;
    __syncthreads();
    int base = blockIdx.x * EPB + t * 8;
    int s[8], d[8];
    int m = 0;
    if (base + 8 <= ne) {
        *(int4*)&s[0] = *(const int4*)(src + base);
        *(int4*)&s[4] = *(const int4*)(src + base + 4);
        *(int4*)&d[0] = *(const int4*)(dst + base);
        *(int4*)&d[4] = *(const int4*)(dst + base + 4);
        m = 8;
    } else if (base < ne) {
        m = ne - base;
        for (int i = 0; i < m; ++i) { s[i] = src[base + i]; d[i] = dst[base + i]; }
    }
    for (int i = 0; i < m; ++i) atomicAdd(&cnt[d[i] >> BSHIFT], 1);
    __syncthreads();
    if (t < NB_BUCKET) {
        gstart[t] = t * BCAP + atomicAdd(&cursor0[t], cnt[t]);
        cur[t] = 0;
    }
    __syncthreads();
    for (int i = 0; i < m; ++i) {
        int b = d[i] >> BSHIFT;
        int l = atomicAdd(&cur[b], 1);
        packed[gstart[b] + l] = ((unsigned)(d[i] & 511) << 16) | (unsigned)s[i];
    }
}

// ---- phase B: one block per bucket; LDS deg+scan -> row_ptr/inv_deg/col -----
// In-block 98-scan of bucket counts gives global offsets; all col writes for a
// bucket come from ONE block into a contiguous region (no write amplification).
__global__ __launch_bounds__(512) void binB_kernel(const unsigned* __restrict__ packed,
                                                   const int* __restrict__ cursor0,
                                                   int* __restrict__ row_ptr,
                                                   float* __restrict__ inv_deg,
                                                   int* __restrict__ col, int n, int ne) {
    __shared__ int sdeg[512];
    __shared__ int scur[512];
    __shared__ int scnt[NB_BUCKET];
    __shared__ int sebeg[NB_BUCKET];
    int b = blockIdx.x, t = threadIdx.x;
    if (t < NB_BUCKET) scnt[t] = cursor0[t];
    sdeg[t] = 0;
    __syncthreads();
    if (t == 0) {                 // serial 98-scan (cheap, per-block)
        int run = 0;
        for (int i = 0; i < NB_BUCKET; ++i) { sebeg[i] = run; run += scnt[i]; }
    }
    __syncthreads();
    int ebeg = sebeg[b];
    int cntE = scnt[b];
    const unsigned* pk = packed + (size_t)b * BCAP;
    for (int e = t; e < cntE; e += 512) atomicAdd(&sdeg[pk[e] >> 16], 1);
    __syncthreads();
    int v = sdeg[t];
    for (int d = 1; d < 512; d <<= 1) {        // inclusive scan, double-barrier
        int u = (t >= d) ? sdeg[t - d] : 0;
        __syncthreads();
        sdeg[t] += u;
        __syncthreads();
    }
    int excl = sdeg[t] - v;
    scur[t] = excl;
    int node = (b << BSHIFT) + t;
    if (node < n) {
        row_ptr[node] = ebeg + excl;
        inv_deg[node] = 1.0f / (float)(v > 0 ? v : 1);
    }
    if (b == 0 && t == 0) row_ptr[n] = ne;
    __syncthreads();
    for (int e = t; e < cntE; e += 512) {
        unsigned w = pk[e];
        int dl = w >> 16;
        int pos = ebeg + atomicAdd(&scur[dl], 1);
        col[pos] = (int)(w & 0xffffu);
    }
}

// ---------------- mean aggregation over bf16, fp32 accumulate, bf16 out ------
__global__ __launch_bounds__(256) void agg_kernel(const unsigned short* __restrict__ hb,
                                                  const int* __restrict__ row_ptr,
                                                  const int* __restrict__ col,
                                                  const float* __restrict__ inv_deg,
                                                  unsigned short* __restrict__ outb, int n) {
    int node = blockIdx.x * 4 + (threadIdx.x >> 6);
    if (node >= n) return;
    int lane = threadIdx.x & 63;
    int slot = lane >> 4, sub = lane & 15;
    int beg = row_ptr[node], end = row_ptr[node + 1];
    const unsigned short* base = hb + (sub << 3);
    float acc[8];
#pragma unroll
    for (int j = 0; j < 8; ++j) acc[j] = 0.f;

    int e = beg + slot;
    for (; e + 4 < end; e += 8) {
        int j0 = col[e];
        int j1 = col[e + 4];
        uint4 v0 = *(const uint4*)(base + ((size_t)j0 << 7));
        uint4 v1 = *(const uint4*)(base + ((size_t)j1 << 7));
        unsigned w0[4] = {v0.x, v0.y, v0.z, v0.w};
        unsigned w1[4] = {v1.x, v1.y, v1.z, v1.w};
#pragma unroll
        for (int d = 0; d < 4; ++d) {
            acc[2 * d + 0] += __uint_as_float(w0[d] << 16);
            acc[2 * d + 1] += __uint_as_float(w0[d] & 0xffff0000u);
            acc[2 * d + 0] += __uint_as_float(w1[d] << 16);
            acc[2 * d + 1] += __uint_as_float(w1[d] & 0xffff0000u);
        }
    }
    if (e < end) {
        int j0 = col[e];
        uint4 v0 = *(const uint4*)(base + ((size_t)j0 << 7));
        unsigned w0[4] = {v0.x, v0.y, v0.z, v0.w};
#pragma unroll
        for (int d = 0; d < 4; ++d) {
            acc[2 * d + 0] += __uint_as_float(w0[d] << 16);
            acc[2 * d + 1] += __uint_as_float(w0[d] & 0xffff0000u);
        }
    }
#pragma unroll
    for (int j = 0; j < 8; ++j) {
        acc[j] += __shfl_xor(acc[j], 16, 64);
        acc[j] += __shfl_xor(acc[j], 32, 64);
    }
    if (slot == 0) {
        float s = inv_deg[node];
        short8 o;
#pragma unroll
        for (int j = 0; j < 8; ++j) o[j] = (short)bf16_rne(acc[j] * s);
        *(short8*)(outb + ((size_t)node << 7) + (sub << 3)) = o;
    }
}

// ---------------- fused dual GEMM, bf16-A x split-bf16-W MFMA (+opt. FC) -----
// A0/A1 read directly as bf16 fragments (no split VALU). W pre-split hi/lo.
__global__ __launch_bounds__(256) void gemm_mfma(const unsigned short* __restrict__ A0b,
                                                 const unsigned short* __restrict__ A1b,
                                                 const short* __restrict__ Wf0,
                                                 const short* __restrict__ Wf1,
                                                 const float* __restrict__ bias,
                                                 unsigned short* __restrict__ outb,
                                                 const float* __restrict__ Wfc,
                                                 const float* __restrict__ bfc,
                                                 float* __restrict__ fcout,
                                                 int n, int relu) {
    int lane = threadIdx.x & 63;
    int wave = threadIdx.x >> 6;
    int quad = lane >> 4, m16 = lane & 15;
    int row_base = blockIdx.x * 64 + wave * 16;
    int arow = row_base + m16;
    if (arow > n - 1) arow = n - 1;            // clamp (padding rows never stored)

    f32x4 acc[8];
#pragma unroll
    for (int nt = 0; nt < 8; ++nt) acc[nt] = (f32x4){0.f, 0.f, 0.f, 0.f};

    const unsigned short* ap0 = A0b + ((size_t)arow << 7) + (quad << 3);
    const unsigned short* ap1 = A1b + ((size_t)arow << 7) + (quad << 3);
#pragma unroll
    for (int kc = 0; kc < 4; ++kc) {
        short8 a0 = *(const short8*)(ap0 + kc * 32);
        short8 a1 = *(const short8*)(ap1 + kc * 32);
        const short* wp0 = Wf0 + ((size_t)kc * 2 * 64 + lane) * 8;
        const short* wp1 = Wf1 + ((size_t)kc * 2 * 64 + lane) * 8;
#pragma unroll
        for (int nt = 0; nt < 8; ++nt) {
            short8 bh0 = *(const short8*)(wp0 + (size_t)nt * 4096);
            short8 bl0 = *(const short8*)(wp0 + (size_t)nt * 4096 + 512);
            short8 bh1 = *(const short8*)(wp1 + (size_t)nt * 4096);
            short8 bl1 = *(const short8*)(wp1 + (size_t)nt * 4096 + 512);
            acc[nt] = __builtin_amdgcn_mfma_f32_16x16x32_bf16(a0, bh0, acc[nt], 0, 0, 0);
            acc[nt] = __builtin_amdgcn_mfma_f32_16x16x32_bf16(a0, bl0, acc[nt], 0, 0, 0);
            acc[nt] = __builtin_amdgcn_mfma_f32_16x16x32_bf16(a1, bh1, acc[nt], 0, 0, 0);
            acc[nt] = __builtin_amdgcn_mfma_f32_16x16x32_bf16(a1, bl1, acc[nt], 0, 0, 0);
        }
    }

    // epilogue: C/D layout col = lane&15, row = quad*4 + reg
    float bcol[8];
#pragma unroll
    for (int nt = 0; nt < 8; ++nt) bcol[nt] = bias[nt * 16 + m16];

    if (Wfc) {
        // fused final FC: lane holds cols nt*16+m16; reduce over 16 m16-lanes
        float w0[8], w1[8];
#pragma unroll
        for (int nt = 0; nt < 8; ++nt) {
            float2 wv = *(const float2*)(Wfc + 2 * (nt * 16 + m16));
            w0[nt] = wv.x;
            w1[nt] = wv.y;
        }
        float b0 = bfc[0], b1 = bfc[1];
#pragma unroll
        for (int r = 0; r < 4; ++r) {
            float p0 = 0.f, p1 = 0.f;
#pragma unroll
            for (int nt = 0; nt < 8; ++nt) {
                float v = fmaxf(acc[nt][r] + bcol[nt], 0.f);   // relu (layer2)
                p0 += v * w0[nt];
                p1 += v * w1[nt];
            }
#pragma unroll
            for (int off = 1; off < 16; off <<= 1) {
                p0 += __shfl_xor(p0, off, 64);
                p1 += __shfl_xor(p1, off, 64);
            }
            int row = row_base + quad * 4 + r;
            if (m16 == 0 && row < n) {
                float2 o;
                o.x = p0 + b0;
                o.y = p1 + b1;
                *(float2*)(fcout + 2 * (size_t)row) = o;
            }
        }
    } else {
#pragma unroll
        for (int r = 0; r < 4; ++r) {
            int row = row_base + quad * 4 + r;
            if (row >= n) continue;
            unsigned short* opb = outb + ((size_t)row << 7) + m16;
#pragma unroll
            for (int nt = 0; nt < 8; ++nt) {
                float v = acc[nt][r] + bcol[nt];
                if (relu) v = fmaxf(v, 0.f);
                opb[nt * 16] = bf16_rne(v);
            }
        }
    }
}

extern "C" void kernel_launch(void* const* d_in, const int* in_sizes, int n_in,
                              void* d_out, int out_size, void* d_ws, size_t ws_size,
                              hipStream_t stream) {
    const float* x   = (const float*)d_in[0];
    const int* edge  = (const int*)d_in[1];
    const float* W1l = (const float*)d_in[2];
    const float* W1r = (const float*)d_in[3];
    const float* b1  = (const float*)d_in[4];
    const float* W2l = (const float*)d_in[5];
    const float* W2r = (const float*)d_in[6];
    const float* b2  = (const float*)d_in[7];
    const float* Wfc = (const float*)d_in[8];
    const float* bfc = (const float*)d_in[9];
    float* out = (float*)d_out;

    const int n = NN, ne = NE;
    const int* src = edge;        // edge_index[0]
    const int* dst = edge + ne;   // edge_index[1]

    char* ws = (char*)d_ws;
    size_t off = 0;
    auto alloc = [&](size_t bytes) -> char* {
        char* p = ws + off;
        off = (off + bytes + 511) & ~(size_t)511;
        return p;
    };
    int* row_ptr     = (int*)alloc((size_t)(n + 1) * 4);
    float* invdeg    = (float*)alloc((size_t)n * 4);
    int* cursor0     = (int*)alloc((size_t)NB_BUCKET * 4);
    short* wf        = (short*)alloc((size_t)4 * 32768 * 2);
    unsigned* packed = (unsigned*)alloc((size_t)NB_BUCKET * BCAP * 4);
    int* col         = (int*)alloc((size_t)ne * 4);
    unsigned short* aggb = (unsigned short*)alloc((size_t)n * 128 * 2);
    unsigned short* xb   = (unsigned short*)alloc((size_t)n * 128 * 2);
    unsigned short* h1b  = (unsigned short*)alloc((size_t)n * 128 * 2);
    (void)ws_size; (void)in_sizes; (void)n_in; (void)out_size;

    setup_kernel<<<SETUP_GRID, 256, 0, stream>>>(x, xb, W1l, W1r, W2l, W2r, wf, cursor0);
    binA_kernel<<<NBLK_E, 256, 0, stream>>>(src, dst, cursor0, packed, ne);
    binB_kernel<<<NB_BUCKET, 512, 0, stream>>>(packed, cursor0, row_ptr, invdeg, col, n, ne);

    agg_kernel<<<(n + 3) / 4, 256, 0, stream>>>(xb, row_ptr, col, invdeg, aggb, n);
    gemm_mfma<<<(n + 63) / 64, 256, 0, stream>>>(aggb, xb, wf, wf + 32768, b1, h1b,
                                                 (const float*)0, (const float*)0, (float*)0, n, 1);
    agg_kernel<<<(n + 3) / 4, 256, 0, stream>>>(h1b, row_ptr, col, invdeg, aggb, n);
    gemm_mfma<<<(n + 63) / 64, 256, 0, stream>>>(aggb, h1b, wf + 2 * 32768, wf + 3 * 32768, b2,
                                                 (unsigned short*)0, Wfc, bfc, out, n, 1);
}